// Round 3
// baseline (197.280 us; speedup 1.0000x reference)
//
#include <hip/hip_runtime.h>
#include <math.h>

#define BATCH 64
#define LSEQ 2048
#define DMOD 256
#define KC 32
#define LCHUNK 256  // l's per block
#define LS 32       // l's per subtile
#define NSUB 8
#define PITCH_D 264 // bf16 pitch for d-fast tiles (256+8: stride 528B -> 2-way banks, free)
#define PITCH_L 40  // bf16 pitch for l-fast tiles (32+8: stride 80B -> 2-way banks, free)

typedef __bf16 bf16x8 __attribute__((ext_vector_type(8)));
typedef __bf16 bf16x4 __attribute__((ext_vector_type(4)));
typedef float f32x4 __attribute__((ext_vector_type(4)));

// One block: (b, 256-l chunk). Computes C_u[32][256] = sum_l exp(s[l,k])*rev[l,d]
// and Z[32] = sum_l exp(s[l,k]) over its chunk (no max subtraction: |s| <~ 7).
// R3: register-prefetch of next subtile to hide HBM latency behind the
// transpose/GEMM1/GEMM2 compute phase of the current subtile.
__global__ __launch_bounds__(256, 2) void fused_pool_kernel(
    const float* __restrict__ rev, const float* __restrict__ W,
    float* __restrict__ cPartial, float* __restrict__ zPartial) {
  __shared__ __align__(16) __bf16 sW[KC * PITCH_D];      // W[k][d], d-fast
  __shared__ __align__(16) __bf16 sRev[LS * PITCH_D];    // rev[l][d], d-fast (GEMM1 B)
  __shared__ __align__(16) __bf16 sRevT[DMOD * PITCH_L]; // rev[d][l], l-fast (GEMM2 B)
  __shared__ __align__(16) __bf16 sP[KC * PITCH_L];      // p[k][l], l-fast (GEMM2 A)
  __shared__ float sZw[2][KC];

  const int tid = threadIdx.x;
  const int b = blockIdx.y;
  const int lc = blockIdx.x;
  const int lbase = lc * LCHUNK;
  const int lane = tid & 63;
  const int wave = tid >> 6;
  const int col = lane & 15;
  const int quad = lane >> 4;

  const int Mt = wave & 1;   // k-half (both GEMMs)
  const int Nt = wave >> 1;  // GEMM1: l-half of subtile; GEMM2: d-half group

  // stage W -> bf16 LDS (once per block; visible after sub-0's barrier B)
#pragma unroll
  for (int i = 0; i < 8; ++i) {
    int flat = tid + 256 * i;
    int kk = flat >> 6, c4 = flat & 63;
    float4 v = *(const float4*)(W + kk * DMOD + c4 * 4);
    bf16x4 h = {(__bf16)v.x, (__bf16)v.y, (__bf16)v.z, (__bf16)v.w};
    *(bf16x4*)(&sW[kk * PITCH_D + c4 * 4]) = h;
  }

  f32x4 acc2[8];
#pragma unroll
  for (int i = 0; i < 8; ++i) acc2[i] = (f32x4){0.f, 0.f, 0.f, 0.f};
  float zacc[4] = {0.f, 0.f, 0.f, 0.f};

  // prologue: prefetch subtile 0 into registers
  float4 pf[8];
#pragma unroll
  for (int i = 0; i < 8; ++i) {
    int slot = tid + 256 * i;
    int r = slot >> 6, c4 = slot & 63;
    pf[i] = *(const float4*)(rev + ((size_t)b * LSEQ + lbase + r) * DMOD + c4 * 4);
  }

  for (int sub = 0; sub < NSUB; ++sub) {
    __syncthreads();  // A: prev GEMM1/GEMM2 done before overwriting sRev/sRevT/sP

    // staging write: regs (fp32) -> bf16 sRev
#pragma unroll
    for (int i = 0; i < 8; ++i) {
      int slot = tid + 256 * i;
      int r = slot >> 6, c4 = slot & 63;
      float4 v = pf[i];
      bf16x4 h = {(__bf16)v.x, (__bf16)v.y, (__bf16)v.z, (__bf16)v.w};
      *(bf16x4*)(&sRev[r * PITCH_D + c4 * 4]) = h;
    }
    __syncthreads();  // B: sRev (and sW on iter 0) visible

    // issue prefetch for sub+1 NOW — overlaps transpose+GEMM1+GEMM2 below
    if (sub + 1 < NSUB) {
      const int l1 = lbase + (sub + 1) * LS;
#pragma unroll
      for (int i = 0; i < 8; ++i) {
        int slot = tid + 256 * i;
        int r = slot >> 6, c4 = slot & 63;
        pf[i] = *(const float4*)(rev + ((size_t)b * LSEQ + l1 + r) * DMOD + c4 * 4);
      }
    }

    // transpose pass: sRev[l][d] -> sRevT[d][l]. u16 column reads (conflict-free:
    // consecutive lanes read consecutive d) + b128 row writes (80B stride, 2-way).
#pragma unroll
    for (int j4 = 0; j4 < 4; ++j4) {
      bf16x8 v;
#pragma unroll
      for (int j = 0; j < 8; ++j) v[j] = sRev[(j4 * 8 + j) * PITCH_D + tid];
      *(bf16x8*)(&sRevT[tid * PITCH_L + j4 * 8]) = v;
    }

    // GEMM1: s^T tile [16 k (Mt)][16 l (Nt)], K=256 over 8 steps.
    // A = W[k][d] (A[m=lane&15][kd=quad*8+j]); B = rev (B[kd=d][n=l]).
    f32x4 acc1 = {0.f, 0.f, 0.f, 0.f};
#pragma unroll
    for (int ks = 0; ks < 8; ++ks) {
      bf16x8 afrag = *(const bf16x8*)(&sW[(Mt * 16 + col) * PITCH_D + ks * 32 + quad * 8]);
      bf16x8 bfrag = *(const bf16x8*)(&sRev[(Nt * 16 + col) * PITCH_D + ks * 32 + quad * 8]);
      acc1 = __builtin_amdgcn_mfma_f32_16x16x32_bf16(afrag, bfrag, acc1, 0, 0, 0);
    }
    // C/D layout: row(m=k) = quad*4+reg, col(n=l) = lane&15.
#pragma unroll
    for (int reg = 0; reg < 4; ++reg) {
      float p = __expf(acc1[reg]);
      __bf16 ph = (__bf16)p;
      zacc[reg] += (float)ph;  // z consistent with bf16-rounded numerator
      sP[(Mt * 16 + quad * 4 + reg) * PITCH_L + Nt * 16 + col] = ph;
    }
    __syncthreads();  // C: sP + sRevT visible

    // GEMM2: C[16 k (Mt)][128 d (Nt-group)], K=32 (one step).
    // A = P^T from sP[k][l-fast]; B = rev from sRevT[d][l-fast].
    bf16x8 pa = *(const bf16x8*)(&sP[(Mt * 16 + col) * PITCH_L + quad * 8]);
#pragma unroll
    for (int nt = 0; nt < 8; ++nt) {
      int dt = Nt * 8 + nt;
      bf16x8 bb = *(const bf16x8*)(&sRevT[(dt * 16 + col) * PITCH_L + quad * 8]);
      acc2[nt] = __builtin_amdgcn_mfma_f32_16x16x32_bf16(pa, bb, acc2[nt], 0, 0, 0);
    }
  }

  // Z: reduce over the 16 col-lanes (l), stash per (Nt) row, combine.
#pragma unroll
  for (int off = 1; off < 16; off <<= 1)
#pragma unroll
    for (int reg = 0; reg < 4; ++reg) zacc[reg] += __shfl_xor(zacc[reg], off, 64);
  if (col == 0) {
#pragma unroll
    for (int reg = 0; reg < 4; ++reg)
      sZw[Nt][Mt * 16 + quad * 4 + reg] = zacc[reg];
  }
  __syncthreads();
  if (tid < KC)
    zPartial[((size_t)b * 8 + lc) * KC + tid] = sZw[0][tid] + sZw[1][tid];

  // C partial store: row(m=k)=quad*4+reg, col(n=d)=lane&15.
  float* dst = cPartial + (((size_t)b * 8 + lc) * KC) * DMOD;
#pragma unroll
  for (int nt = 0; nt < 8; ++nt) {
    int d = (Nt * 8 + nt) * 16 + col;
#pragma unroll
    for (int reg = 0; reg < 4; ++reg) {
      int k = Mt * 16 + quad * 4 + reg;
      dst[k * DMOD + d] = acc2[nt][reg];
    }
  }
}

// out[b][k][d] = (sum_lc C_u) / (sum_lc Z), float4-vectorized
__global__ __launch_bounds__(256) void reduce_kernel(
    const float* __restrict__ cPartial, const float* __restrict__ zPartial,
    float* __restrict__ out) {
  int idx = blockIdx.x * 256 + threadIdx.x;  // 131072 float4 slots
  int b = idx >> 11;
  int k = (idx >> 6) & 31;
  float4 s = {0.f, 0.f, 0.f, 0.f};
  float z = 0.f;
#pragma unroll
  for (int lcc = 0; lcc < 8; ++lcc) {
    const float4 v = *(const float4*)(cPartial + ((((size_t)b * 8 + lcc) * KC + k) << 8) +
                                      ((idx & 63) << 2));
    s.x += v.x; s.y += v.y; s.z += v.z; s.w += v.w;
    z += zPartial[((size_t)b * 8 + lcc) * KC + k];
  }
  float zi = 1.0f / z;
  float4 o = {s.x * zi, s.y * zi, s.z * zi, s.w * zi};
  *(float4*)(out + ((size_t)idx << 2)) = o;
}

extern "C" void kernel_launch(void* const* d_in, const int* in_sizes, int n_in,
                              void* d_out, int out_size, void* d_ws,
                              size_t ws_size, hipStream_t stream) {
  const float* rev = (const float*)d_in[0];  // 64*2048*256 fp32
  const float* W = (const float*)d_in[1];    // 32*256 fp32
  float* out = (float*)d_out;                // 64*32*256 fp32

  float* ws = (float*)d_ws;
  float* cPartial = ws;                                        // 64*8*32*256 floats
  float* zPartial = cPartial + (size_t)BATCH * 8 * KC * DMOD;  // 64*8*32 floats

  fused_pool_kernel<<<dim3(8, BATCH), dim3(256), 0, stream>>>(rev, W, cPartial,
                                                              zPartial);
  reduce_kernel<<<dim3(512), dim3(256), 0, stream>>>(cPartial, zPartial, out);
}